// Round 3
// baseline (54.775 us; speedup 1.0000x reference)
//
#include <hip/hip_runtime.h>

// Problem constants: B=32, M=12, T=512, G=256
#define B_ 32
#define M_ 12
#define T_ 512
#define G_ 256

#define GS 16             // g-values per block
#define NCHUNK (G_ / GS)  // grid (32,16) = 512 blocks

// LDS phases (aliased):
//  Phase 1 (main): rows lds16[t*24 + slot], t in [0,512): 24 bf16 per row =
//     3 slots x (4 y-bf16 + 4 mask-bf16) = 48B/row, physical slot rotated by
//     (t>>3)%3 so the main-loop b128 reads are ~2-way conflicts (free).
//     Uses 24 KB.
//  Phase 2 (reduce): float rows red[tid][0..47], stride 52 floats. 53 KB.
#define RED_STRIDE 52
#define LDS_FLOATS 13312   // 256*52

// out[b][g][2m+0] = dens = sum_t mask[b,m,t]*exp(-0.5*(grid[g]-x[b,t])^2/s0^2)
// out[b][g][2m+1] = conv/(dens+1e-8), conv = sum_t y[b,m,t]*exp(-0.5*(..)^2/s1^2)

__device__ __forceinline__ float bf_lo(unsigned int u) {
    return __uint_as_float(u << 16);
}
__device__ __forceinline__ float bf_hi(unsigned int u) {
    return __uint_as_float(u & 0xffff0000u);
}
__device__ __forceinline__ unsigned short to_bf16_rne(float f) {
    unsigned int u = __float_as_uint(f);
    u += 0x7fffu + ((u >> 16) & 1u);   // round-to-nearest-even
    return (unsigned short)(u >> 16);
}

__global__ __launch_bounds__(256, 3) void k_fused(
    const float* __restrict__ y, const float* __restrict__ x,
    const int* __restrict__ mask, const float* __restrict__ grid,
    const float* __restrict__ sigma, float* __restrict__ out)
{
    __shared__ float lds[LDS_FLOATS];
    unsigned short* lds16 = (unsigned short*)lds;
    unsigned int*   lds32 = (unsigned int*)lds;

    const int b     = blockIdx.x;
    const int gbase = blockIdx.y * GS;
    const int tid   = threadIdx.x;
    const int gq    = tid >> 5;   // 0..7  (owns g = gbase+gq, gbase+gq+8)
    const int ts    = tid & 31;   // t-slice: t = ts + 32k

    // ---- x -> registers (coalesced; issued early, consumed after sync) ----
    float xr[16];
#pragma unroll
    for (int k = 0; k < 16; ++k) xr[k] = x[b * T_ + ts + 32 * k];

    // ---- stage y+mask as bf16, [m][t] read order => coalesced global ----
    for (int i = tid; i < T_ * M_; i += 256) {
        const int m = i >> 9;        // i / 512
        const int t = i & 511;       // i % 512
        const int q = m >> 2, p = m & 3;
        int qq = q + ((t >> 3) % 3);
        if (qq >= 3) qq -= 3;
        const int base = t * 24 + (qq << 3);
        lds16[base + p]     = to_bf16_rne(y[(b * M_ + m) * T_ + t]);
        lds16[base + 4 + p] = mask[(b * M_ + m) * T_ + t] ? (unsigned short)0x3F80u
                                                          : (unsigned short)0u;
    }
    __syncthreads();

    const float gv0 = grid[gbase + gq];
    const float gv1 = grid[gbase + gq + 8];
    const float s0 = sigma[0], s1 = sigma[1];
    const float LOG2E = 1.4426950408889634f;
    const float c0 = (-0.5f / (s0 * s0)) * LOG2E;
    const float c1 = (-0.5f / (s1 * s1)) * LOG2E;

    float2 acc[2][12];
#pragma unroll
    for (int h = 0; h < 2; ++h)
#pragma unroll
        for (int m = 0; m < M_; ++m) acc[h][m] = make_float2(0.f, 0.f);

#pragma unroll
    for (int k = 0; k < 16; ++k) {
        const int t = ts + 32 * k;
        const float xv = xr[k];
        const float d0 = gv0 - xv, d1 = gv1 - xv;
        const float p0 = d0 * d0,  p1 = d1 * d1;
        const float e00 = __builtin_amdgcn_exp2f(p0 * c0);
        const float e01 = __builtin_amdgcn_exp2f(p0 * c1);
        const float e10 = __builtin_amdgcn_exp2f(p1 * c0);
        const float e11 = __builtin_amdgcn_exp2f(p1 * c1);
        const int r = (t >> 3) % 3;
        const int row = t * 12;                 // u32 index of row
#pragma unroll
        for (int q = 0; q < 3; ++q) {
            int qq = q + r; if (qq >= 3) qq -= 3;
            const uint4 v = *(const uint4*)&lds32[row + (qq << 2)];
            float yv[4], mv[4];
            yv[0] = bf_lo(v.x); yv[1] = bf_hi(v.x);
            yv[2] = bf_lo(v.y); yv[3] = bf_hi(v.y);
            mv[0] = bf_lo(v.z); mv[1] = bf_hi(v.z);
            mv[2] = bf_lo(v.w); mv[3] = bf_hi(v.w);
#pragma unroll
            for (int p = 0; p < 4; ++p) {
                const int m = q * 4 + p;
                acc[0][m].x += mv[p] * e00;
                acc[0][m].y += yv[p] * e01;
                acc[1][m].x += mv[p] * e10;
                acc[1][m].y += yv[p] * e11;
            }
        }
    }

    // ---- reduce over the 32 t-slices per g ----
    __syncthreads();  // all reads of staged data done before overwrite
    {
        const float4* av = (const float4*)&acc[0][0];
#pragma unroll
        for (int j = 0; j < 12; ++j)
            *(float4*)&lds[tid * RED_STRIDE + 4 * j] = av[j];
    }
    __syncthreads();

    if (tid < GS * M_) {            // 192 finalize threads: one (g,m) each
        const int og = tid / 12;    // 0..15 -> g = gbase + og
        const int m  = tid - og * 12;
        const int h  = og >> 3;
        const int q8 = og & 7;
        float dens = 0.f, conv = 0.f;
#pragma unroll
        for (int t5 = 0; t5 < 32; ++t5) {
            const float2 v = *(const float2*)&lds[(q8 * 32 + t5) * RED_STRIDE
                                                  + 2 * (h * 12 + m)];
            dens += v.x;
            conv += v.y;
        }
        float2 o;
        o.x = dens;
        o.y = conv / (dens + 1e-8f);
        *(float2*)&out[(size_t)((b * G_ + gbase + og) * 2 * M_) + 2 * m] = o;
    }
}

extern "C" void kernel_launch(void* const* d_in, const int* in_sizes, int n_in,
                              void* d_out, int out_size, void* d_ws, size_t ws_size,
                              hipStream_t stream) {
    const float* y     = (const float*)d_in[0];
    const float* x     = (const float*)d_in[1];
    const int*   mask  = (const int*)d_in[2];
    const float* grid  = (const float*)d_in[3];
    const float* sigma = (const float*)d_in[4];
    float* out = (float*)d_out;

    k_fused<<<dim3(B_, NCHUNK), 256, 0, stream>>>(y, x, mask, grid, sigma, out);
}

// Round 4
// 15.963 us; speedup vs baseline: 3.4313x; 3.4313x over previous
//
#include <hip/hip_runtime.h>

// Problem constants: B=32, M=12, T=512, G=256
#define B_ 32
#define M_ 12
#define T_ 512
#define G_ 256

#define GS 16              // g-values per block
#define NBLK 512           // B_ * (G_/GS)

// LDS (aliased phases):
//  Phase 1 (staging/main): lds32[t*13 + m], t<512, m<12 — one u32 per (t,m):
//     high 16 = bf16(y), low 16 = bf16(mask). Row stride 13 words (odd) ->
//     conflict-free scatter writes AND conflict-free lane-over-t reads.
//     26,624 B.
//  Phase 2 (reduce): red[tid][52 floats], slot-rotated to kill the stride-52
//     8-way write conflict. 53,248 B total.
#define ROWW 13
#define RED_STRIDE 52
#define LDS_FLOATS (256 * RED_STRIDE)

// out[b][g][2m+0] = dens = sum_t mask[b,m,t]*exp(-0.5*(grid[g]-x[b,t])^2/s0^2)
// out[b][g][2m+1] = conv/(dens+1e-8), conv = sum_t y[b,m,t]*exp(-0.5*(..)^2/s1^2)

__device__ __forceinline__ unsigned short to_bf16_rne(float f) {
    unsigned int u = __float_as_uint(f);
    u += 0x7fffu + ((u >> 16) & 1u);   // round-to-nearest-even
    return (unsigned short)(u >> 16);
}

__global__ __launch_bounds__(256, 2) void k_fused(
    const float* __restrict__ y, const float* __restrict__ x,
    const int* __restrict__ mask, const float* __restrict__ grid,
    const float* __restrict__ sigma, float* __restrict__ out)
{
    __shared__ float lds[LDS_FLOATS];
    unsigned int* lds32 = (unsigned int*)lds;

    // XCD-pinned work mapping (hw xcd ~= blockIdx.x % 8): each XCD gets
    // 4 consecutive b's with ALL their g-chunks -> y/mask L2-resident.
    const int w     = ((blockIdx.x & 7) << 6) | (blockIdx.x >> 3);  // bijective
    const int b     = w >> 4;          // 0..31
    const int gbase = (w & 15) * GS;   // 0,16,...,240

    const int tid = threadIdx.x;
    const int gq  = tid >> 5;   // 0..7: owns g = gbase+gq and gbase+gq+8
    const int ts  = tid & 31;   // t-slice: t = ts + 32k

    // ---- x -> registers (coalesced 128B/load, consumed after sync) ----
    float xr[16];
#pragma unroll
    for (int k = 0; k < 16; ++k) xr[k] = x[b * T_ + ts + 32 * k];

    // ---- stage y+mask packed u32; [m][t] order => coalesced global reads;
    //      LDS scatter at odd row stride => conflict-free writes ----
#pragma unroll 8
    for (int i = tid; i < T_ * M_; i += 256) {
        const int m = i >> 9;        // i / 512
        const int t = i & 511;       // i % 512
        const unsigned int yb = (unsigned int)to_bf16_rne(y[(b * M_ + m) * T_ + t]) << 16;
        const unsigned int mb = mask[(b * M_ + m) * T_ + t] ? 0x3F80u : 0u;
        lds32[t * ROWW + m] = yb | mb;
    }
    __syncthreads();

    const float gv0 = grid[gbase + gq];
    const float gv1 = grid[gbase + gq + 8];
    const float s0 = sigma[0], s1 = sigma[1];
    const float LOG2E = 1.4426950408889634f;
    const float c0 = (-0.5f / (s0 * s0)) * LOG2E;
    const float c1 = (-0.5f / (s1 * s1)) * LOG2E;

    float2 acc[2][12];
#pragma unroll
    for (int h = 0; h < 2; ++h)
#pragma unroll
        for (int m = 0; m < M_; ++m) acc[h][m] = make_float2(0.f, 0.f);

#pragma unroll
    for (int k = 0; k < 16; ++k) {
        const int t  = ts + 32 * k;
        const float xv = xr[k];
        const float d0 = gv0 - xv, d1 = gv1 - xv;
        const float p0 = d0 * d0,  p1 = d1 * d1;
        const float e00 = __builtin_amdgcn_exp2f(p0 * c0);
        const float e01 = __builtin_amdgcn_exp2f(p0 * c1);
        const float e10 = __builtin_amdgcn_exp2f(p1 * c0);
        const float e11 = __builtin_amdgcn_exp2f(p1 * c1);
        const unsigned int* row = &lds32[t * ROWW];
#pragma unroll
        for (int m = 0; m < M_; ++m) {
            const unsigned int u = row[m];
            const float yv = __uint_as_float(u & 0xffff0000u);
            const float mv = __uint_as_float(u << 16);
            acc[0][m].x += mv * e00;  acc[0][m].y += yv * e01;
            acc[1][m].x += mv * e10;  acc[1][m].y += yv * e11;
        }
    }

    // ---- reduce over the 32 t-slices per g ----
    __syncthreads();   // all staged reads done before overwrite
    {
        // slot rotation r=3*((tid>>3)&3): colliding lane quad {l,l+8,l+16,l+24}
        // -> slots {j,j+3,j+6,j+9} mod 12, disjoint 16B bank spans. No conflicts.
        const float4* av = (const float4*)&acc[0][0];
        const int r = 3 * ((tid >> 3) & 3);
#pragma unroll
        for (int j = 0; j < 12; ++j) {
            int s = j + r; if (s >= 12) s -= 12;
            *(float4*)&lds[tid * RED_STRIDE + 4 * s] = av[j];
        }
    }
    __syncthreads();

    if (tid < GS * M_) {            // 192 finalize threads: one (g,m) each
        const int og = tid / 12;    // 0..15 -> g = gbase + og
        const int m  = tid - og * 12;
        const int h  = og >> 3;     // g-half
        const int q8 = og & 7;      // writer gq
        const int p  = h * 12 + m;  // logical float2 index in acc
        const int j  = p >> 1;      // logical float4 slot
        float dens = 0.f, conv = 0.f;
#pragma unroll
        for (int t5 = 0; t5 < 32; ++t5) {
            const int wl = q8 * 32 + t5;            // writer lane
            int s = j + 3 * ((wl >> 3) & 3); if (s >= 12) s -= 12;
            const float2 v = *(const float2*)&lds[wl * RED_STRIDE + 4 * s + 2 * (p & 1)];
            dens += v.x;
            conv += v.y;
        }
        float2 o;
        o.x = dens;
        o.y = conv / (dens + 1e-8f);
        *(float2*)&out[(size_t)((b * G_ + gbase + og) * 2 * M_) + 2 * m] = o;
    }
}

extern "C" void kernel_launch(void* const* d_in, const int* in_sizes, int n_in,
                              void* d_out, int out_size, void* d_ws, size_t ws_size,
                              hipStream_t stream) {
    const float* y     = (const float*)d_in[0];
    const float* x     = (const float*)d_in[1];
    const int*   mask  = (const int*)d_in[2];
    const float* grid  = (const float*)d_in[3];
    const float* sigma = (const float*)d_in[4];
    float* out = (float*)d_out;

    k_fused<<<NBLK, 256, 0, stream>>>(y, x, mask, grid, sigma, out);
}

// Round 6
// 13.269 us; speedup vs baseline: 4.1281x; 1.2031x over previous
//
#include <hip/hip_runtime.h>

// Problem constants: B=32, M=12, T=512, G=256
#define B_ 32
#define M_ 12
#define T_ 512
#define G_ 256

#define GS 32              // g-values per block
#define NBLK 256           // 32 b * 8 g-chunks
#define TPAIR 256          // T/2 t-pairs
#define ROWW 18            // u32 row stride: odd-in-2-word-units -> b64 reads
                           // hit 16 distinct bank windows (4 lanes each = floor)

// dens[b,g,m] = sum_t mask[b,m,t]*exp(-0.5*(grid[g]-x[b,t])^2/s0^2)
// conv[b,g,m] = sum_t    y[b,m,t]*exp(-0.5*(grid[g]-x[b,t])^2/s1^2)
// out[b][g][2m] = dens ; out[b][g][2m+1] = conv/(dens+1e-8)

using h2 = decltype(__builtin_amdgcn_cvt_pkrtz(0.f, 0.f));

__device__ __forceinline__ float fdot2f(h2 a, h2 b, float c) {
#if __has_builtin(__builtin_amdgcn_fdot2)
    return __builtin_amdgcn_fdot2(a, b, c, false);
#else
    return c + (float)a[0] * (float)b[0] + (float)a[1] * (float)b[1];
#endif
}

// One butterfly step for d<=16 (ds_swizzle xor within 32-lane groups).
template <int D, int N, int IMM>
__device__ __forceinline__ void red_step(float2* U, int ls) {
    const bool bit = (ls & D) != 0;
#pragma unroll
    for (int i = 0; i < N / 2; ++i) {
        const float2 lo = U[i], hi = U[i + N / 2];
        const float2 snd = bit ? lo : hi;
        float2 rcv;
        rcv.x = __uint_as_float(
            (unsigned)__builtin_amdgcn_ds_swizzle((int)__float_as_uint(snd.x), IMM));
        rcv.y = __uint_as_float(
            (unsigned)__builtin_amdgcn_ds_swizzle((int)__float_as_uint(snd.y), IMM));
        const float2 kp = bit ? hi : lo;
        U[i] = make_float2(kp.x + rcv.x, kp.y + rcv.y);
    }
}

// d=32 step: permlane32_swap (VALU pipe) with shfl fallback.
// With both operands = snd: ret[0][ls] = snd[ls & 31], ret[1][ls] = snd[ls | 32].
// Partner value snd[ls^32] is ret[1] for lanes<32 (bit=0), ret[0] for lanes>=32.
__device__ __forceinline__ void red_step32(float2* U, int ls) {
    const bool bit = (ls & 32) != 0;
#pragma unroll
    for (int i = 0; i < 32; ++i) {
        const float2 lo = U[i], hi = U[i + 32];
        const float2 snd = bit ? lo : hi;
        float2 rcv;
#if __has_builtin(__builtin_amdgcn_permlane32_swap)
        {
            auto rx = __builtin_amdgcn_permlane32_swap(
                __float_as_uint(snd.x), __float_as_uint(snd.x), false, false);
            auto ry = __builtin_amdgcn_permlane32_swap(
                __float_as_uint(snd.y), __float_as_uint(snd.y), false, false);
            rcv.x = __uint_as_float(bit ? rx[0] : rx[1]);   // FIXED selector
            rcv.y = __uint_as_float(bit ? ry[0] : ry[1]);   // FIXED selector
        }
#else
        rcv.x = __shfl_xor(snd.x, 32, 64);
        rcv.y = __shfl_xor(snd.y, 32, 64);
#endif
        const float2 kp = bit ? hi : lo;
        U[i] = make_float2(kp.x + rcv.x, kp.y + rcv.y);
    }
}

__global__ __launch_bounds__(512, 2) void k_fused(
    const float* __restrict__ y, const float* __restrict__ x,
    const int* __restrict__ mask, const float* __restrict__ grid,
    const float* __restrict__ sigma, float* __restrict__ out)
{
    __shared__ unsigned int sy[TPAIR * ROWW];   // f16(y) pairs, [tp][m]
    __shared__ unsigned int sm[TPAIR * ROWW];   // f16(mask) pairs

    // XCD-pinned mapping: xcd = bid&7 owns 32 blocks = 4 consecutive b's.
    const int bid = blockIdx.x;
    const int w   = ((bid & 7) << 5) | (bid >> 3);
    const int b   = w >> 3;           // 0..31
    const int gb  = (w & 7) * GS;     // g-chunk base

    const int tid = threadIdx.x;
    const int gq  = tid >> 6;         // wave id 0..7
    const int ls  = tid & 63;         // lane: t-slice

    // x pairs -> registers (coalesced)
    float2 xp[4];
#pragma unroll
    for (int k = 0; k < 4; ++k)
        xp[k] = *(const float2*)&x[b * T_ + 2 * (ls + 64 * k)];

    // stage y+mask as f16 pairs; coalesced float2/int2 global reads
#pragma unroll
    for (int it = 0; it < 6; ++it) {
        const int i  = tid + 512 * it;
        const int m  = i >> 8;        // 0..11
        const int tp = i & 255;
        const float2 yv = *(const float2*)&y[(b * M_ + m) * T_ + 2 * tp];
        auto yh = __builtin_amdgcn_cvt_pkrtz(yv.x, yv.y);
        sy[tp * ROWW + m] = __builtin_bit_cast(unsigned int, yh);
        const int2 mv = *(const int2*)&mask[(b * M_ + m) * T_ + 2 * tp];
        sm[tp * ROWW + m] = (mv.x ? 0x3C00u : 0u) | (mv.y ? 0x3C000000u : 0u);
    }
    __syncthreads();

    float gv[4];
#pragma unroll
    for (int h = 0; h < 4; ++h) gv[h] = grid[gb + gq + 8 * h];
    const float s0 = sigma[0], s1 = sigma[1];
    const float LOG2E = 1.4426950408889634f;
    const float c0 = (-0.5f / (s0 * s0)) * LOG2E;
    const float c1 = (-0.5f / (s1 * s1)) * LOG2E;

    float accD[4][12], accC[4][12];
#pragma unroll
    for (int h = 0; h < 4; ++h)
#pragma unroll
        for (int m = 0; m < 12; ++m) { accD[h][m] = 0.f; accC[h][m] = 0.f; }

#pragma unroll
    for (int k = 0; k < 4; ++k) {
        const int tp = ls + 64 * k;
        const float2 xv = xp[k];
        h2 w0[4], w1[4];
#pragma unroll
        for (int h = 0; h < 4; ++h) {
            const float d0 = gv[h] - xv.x, d1 = gv[h] - xv.y;
            const float p0 = d0 * d0, p1 = d1 * d1;
            w0[h] = __builtin_amdgcn_cvt_pkrtz(__builtin_amdgcn_exp2f(p0 * c0),
                                               __builtin_amdgcn_exp2f(p1 * c0));
            w1[h] = __builtin_amdgcn_cvt_pkrtz(__builtin_amdgcn_exp2f(p0 * c1),
                                               __builtin_amdgcn_exp2f(p1 * c1));
        }
        const unsigned int* ry = &sy[tp * ROWW];
        const unsigned int* rm = &sm[tp * ROWW];
#pragma unroll
        for (int j = 0; j < 6; ++j) {
            const uint2 yv2 = *(const uint2*)&ry[2 * j];   // b64, 8B-aligned
            const uint2 mv2 = *(const uint2*)&rm[2 * j];
            const h2 yp0 = __builtin_bit_cast(h2, yv2.x);
            const h2 yp1 = __builtin_bit_cast(h2, yv2.y);
            const h2 mp0 = __builtin_bit_cast(h2, mv2.x);
            const h2 mp1 = __builtin_bit_cast(h2, mv2.y);
#pragma unroll
            for (int h = 0; h < 4; ++h) {
                accD[h][2 * j]     = fdot2f(mp0, w0[h], accD[h][2 * j]);
                accC[h][2 * j]     = fdot2f(yp0, w1[h], accC[h][2 * j]);
                accD[h][2 * j + 1] = fdot2f(mp1, w0[h], accD[h][2 * j + 1]);
                accC[h][2 * j + 1] = fdot2f(yp1, w1[h], accC[h][2 * j + 1]);
            }
        }
    }

    // ---- 6-step payload-halving butterfly across the 64 t-lanes ----
    // unit u = h*16 + mm (mm<12 real); after steps lane ls owns unit u = ls.
    float2 U[64];
#pragma unroll
    for (int h = 0; h < 4; ++h)
#pragma unroll
        for (int mm = 0; mm < 16; ++mm)
            U[h * 16 + mm] = (mm < 12) ? make_float2(accD[h][mm], accC[h][mm])
                                       : make_float2(0.f, 0.f);

    red_step32(U, ls);
    red_step<16, 32, 0x401F>(U, ls);
    red_step<8,  16, 0x201F>(U, ls);
    red_step<4,   8, 0x101F>(U, ls);
    red_step<2,   4, 0x081F>(U, ls);
    red_step<1,   2, 0x041F>(U, ls);

    const int mm = ls & 15;
    const int h  = ls >> 4;
    if (mm < 12) {
        const int g = gb + gq + 8 * h;
        const float dens = U[0].x;
        float2 o;
        o.x = dens;
        o.y = U[0].y / (dens + 1e-8f);
        *(float2*)&out[(size_t)(b * G_ + g) * (2 * M_) + 2 * mm] = o;
    }
}

extern "C" void kernel_launch(void* const* d_in, const int* in_sizes, int n_in,
                              void* d_out, int out_size, void* d_ws, size_t ws_size,
                              hipStream_t stream) {
    const float* y     = (const float*)d_in[0];
    const float* x     = (const float*)d_in[1];
    const int*   mask  = (const int*)d_in[2];
    const float* grid  = (const float*)d_in[3];
    const float* sigma = (const float*)d_in[4];
    float* out = (float*)d_out;
    (void)d_ws; (void)ws_size;

    k_fused<<<NBLK, 512, 0, stream>>>(y, x, mask, grid, sigma, out);
}